// Round 1
// baseline (286.928 us; speedup 1.0000x reference)
//
#include <hip/hip_runtime.h>
#include <hip/hip_cooperative_groups.h>

namespace cg = cooperative_groups;

#define EPS 1e-5f

#define BATCH 16
#define LEN   1024
#define C0    8
#define C1    32
#define C2    64
#define NODES 128
#define NF1   100
#define NF2   128

// workspace layout (float offsets) — every word read is written earlier in the
// same iteration (safe under harness re-poison), no memset needed.
#define OFF_C1   0          // 16*32*1024  = 524288
#define OFF_C2   524288     // 16*64*1024  = 1048576
#define OFF_Z    1572864    // 16*128*64   = 131072 (zeroed in phase A)
#define OFF_S1P  1703936    // 256 blocks * 64  (BN1 partial s,q per channel)
#define OFF_S2P  1720320    // 256 blocks * 128 (BN2 partial s,q per channel)
#define OFF_ZZP  1753088    // 2 * 16 * 100     (FC1 partials)

__global__ __launch_bounds__(256)
void fused(const float* __restrict__ x, const float* __restrict__ bmat,
           const float* __restrict__ c1w, const float* __restrict__ c1b,
           const float* __restrict__ g1, const float* __restrict__ bb1,
           const float* __restrict__ c2w, const float* __restrict__ c2b,
           const float* __restrict__ g2, const float* __restrict__ bb2,
           const float* __restrict__ w1, const float* __restrict__ b1,
           const float* __restrict__ g3, const float* __restrict__ b3,
           const float* __restrict__ w2, const float* __restrict__ b2,
           float* __restrict__ out, float* __restrict__ ws)
{
    cg::grid_group grid = cg::this_grid();
    const int tid  = threadIdx.x;
    const int b    = blockIdx.x;
    const int lane = tid & 63;
    const int wave = tid >> 6;

    float* c1  = ws + OFF_C1;
    float* c2  = ws + OFF_C2;
    float* z   = ws + OFF_Z;
    float* s1p = ws + OFF_S1P;
    float* s2p = ws + OFF_S2P;
    float* zzp = ws + OFF_ZZP;

    __shared__ __align__(16) float smem[6656];   // 26.6 KB, re-carved per phase

    // ================= Phase A: zero z; conv1 (8->32,K=5) + BN1 partial stats
    {
        // zero z (needed for atomicMax in phase C): 131072 floats / 65536 thr
        int gi = b * 256 + tid;
        z[gi]          = 0.f;
        z[gi + 65536]  = 0.f;

        int n  = b >> 4, lt = b & 15;
        int l  = lt * 64 + lane;
        int cg8 = __builtin_amdgcn_readfirstlane(wave * 8);  // 8 channels/wave

        float xr[5][8];
#pragma unroll
        for (int dl = 0; dl < 5; ++dl) {
            int lw = l + dl - 2;
            if (lw >= 0 && lw < LEN) {
                const float4* p = (const float4*)(x + ((size_t)n * LEN + lw) * C0);
                float4 a = p[0], b4 = p[1];
                xr[dl][0] = a.x;  xr[dl][1] = a.y;  xr[dl][2] = a.z;  xr[dl][3] = a.w;
                xr[dl][4] = b4.x; xr[dl][5] = b4.y; xr[dl][6] = b4.z; xr[dl][7] = b4.w;
            } else {
#pragma unroll
                for (int ci = 0; ci < 8; ++ci) xr[dl][ci] = 0.f;
            }
        }
#pragma unroll
        for (int u = 0; u < 8; ++u) {
            int c = cg8 + u;
            float acc = c1b[c];
            const float* wc = c1w + c * 40;       // wave-uniform -> s_loads
#pragma unroll
            for (int ci = 0; ci < 8; ++ci)
#pragma unroll
                for (int dl = 0; dl < 5; ++dl)
                    acc += xr[dl][ci] * wc[ci * 5 + dl];
            c1[((size_t)n * C1 + c) * LEN + l] = acc;

            float s = acc, q = acc * acc;
#pragma unroll
            for (int off = 32; off >= 1; off >>= 1) {
                s += __shfl_xor(s, off);
                q += __shfl_xor(q, off);
            }
            if (lane == 0) {
                s1p[b * 64 + c * 2]     = s;
                s1p[b * 64 + c * 2 + 1] = q;
            }
        }
    }
    grid.sync();

    // ================= Phase B: BN1 reduce; BN1+ReLU -> conv2 (32->64) + BN2 partials
    {
        float* sc1  = smem;          // 32
        float* sh1  = smem + 32;     // 32
        float* a1   = smem + 64;     // 32*68 = 2176, ends 2240
        float* redw = smem + 2240;   // 4*64 = 256 (stats partial per-wave sums)

        // each wave sums 64 blocks' partials for value v = lane (coalesced)
        {
            float s = 0.f;
            int bb0 = wave * 64;
#pragma unroll 4
            for (int i = 0; i < 64; ++i)
                s += s1p[(size_t)(bb0 + i) * 64 + lane];
            redw[wave * 64 + lane] = s;
        }
        __syncthreads();
        if (tid < 64)
            redw[tid] = redw[tid] + redw[64 + tid] + redw[128 + tid] + redw[192 + tid];
        __syncthreads();
        if (tid < 32) {
            float s = redw[tid * 2], q = redw[tid * 2 + 1];
            float mean = s * (1.f / 16384.f);
            float var  = q * (1.f / 16384.f) - mean * mean;
            float rs   = rsqrtf(var + EPS);
            float sc   = g1[tid] * rs;
            sc1[tid] = sc;
            sh1[tid] = bb1[tid] - mean * sc;
        }
        __syncthreads();

        int n = b >> 4, lt = b & 15;
        int lbase = lt * 64;

        for (int idx = tid; idx < 32 * 68; idx += 256) {
            int ci = idx / 68, lo = idx - ci * 68;
            int lg = lbase + lo - 2;
            float v = 0.f;
            if (lg >= 0 && lg < LEN) v = c1[((size_t)n * C1 + ci) * LEN + lg];
            a1[idx] = fmaxf(0.f, v * sc1[ci] + sh1[ci]);
        }
        __syncthreads();

        int l = lane;
        int cobase = __builtin_amdgcn_readfirstlane(wave * 16);

        float acc[16];
#pragma unroll
        for (int u = 0; u < 16; ++u) acc[u] = c2b[cobase + u];

        for (int ci = 0; ci < 32; ++ci) {
            float v0 = a1[ci * 68 + l + 0];
            float v1 = a1[ci * 68 + l + 1];
            float v2 = a1[ci * 68 + l + 2];
            float v3 = a1[ci * 68 + l + 3];
            float v4 = a1[ci * 68 + l + 4];
#pragma unroll
            for (int u = 0; u < 16; ++u) {
                const float* wp = c2w + ((size_t)(cobase + u) * 32 + ci) * 5;
                acc[u] += v0 * wp[0] + v1 * wp[1] + v2 * wp[2] + v3 * wp[3] + v4 * wp[4];
            }
        }

        int lg = lbase + l;
#pragma unroll
        for (int u = 0; u < 16; ++u)
            c2[((size_t)n * C2 + cobase + u) * LEN + lg] = acc[u];

        for (int u = 0; u < 16; ++u) {
            float s = acc[u], q = acc[u] * acc[u];
#pragma unroll
            for (int off = 32; off >= 1; off >>= 1) {
                s += __shfl_xor(s, off);
                q += __shfl_xor(q, off);
            }
            if (lane == 0) {
                int c = cobase + u;
                s2p[b * 128 + c * 2]     = s;
                s2p[b * 128 + c * 2 + 1] = q;
            }
        }
    }
    grid.sync();

    // ================= Phase C: BN2 reduce; BN2+ReLU + max-product pooling
    {
        float* sc2  = smem;          // 64
        float* sh2  = smem + 64;     // 64
        float* bt   = smem + 128;    // 64*34 = 2176, ends 2304
        float* ht   = smem + 2304;   // 64*68 = 4352, ends 6656
        float* red2 = smem + 128;    // 2*128, reuses bt region (done before staging)

        {
            int v = tid & 127, half = tid >> 7;
            float s = 0.f;
            int bb0 = half * 128;
#pragma unroll 4
            for (int i = 0; i < 128; ++i)
                s += s2p[(size_t)(bb0 + i) * 128 + v];
            red2[half * 128 + v] = s;
        }
        __syncthreads();
        if (tid < 128) red2[tid] += red2[128 + tid];
        __syncthreads();
        if (tid < 64) {
            float s = red2[tid * 2], q = red2[tid * 2 + 1];
            float mean = s * (1.f / 16384.f);
            float var  = q * (1.f / 16384.f) - mean * mean;
            float rs   = rsqrtf(var + EPS);
            float sc   = g2[tid] * rs;
            sc2[tid] = sc;
            sh2[tid] = bb2[tid] - mean * sc;
        }
        __syncthreads();

        int jt = b & 3, is = (b >> 2) & 3, n = b >> 4;
        int jbase = jt * 32;
        int ibase0 = is * 256;

        float mx[2][4];
#pragma unroll
        for (int a = 0; a < 2; ++a)
#pragma unroll
            for (int c = 0; c < 4; ++c) mx[a][c] = 0.f;

        int jj = (tid >> 4) * 2, kk = (tid & 15) * 4;

        for (int ic = 0; ic < 4; ++ic) {
            int ib = ibase0 + ic * 64;
            {   // stage b tile [64 i][32 j], pad stride 34
                int il = tid >> 2, jq = tid & 3;
                const float4* p = (const float4*)(bmat + ((size_t)n * LEN + ib + il) * NODES + jbase + jq * 8);
                float4 a = p[0], b4 = p[1];
                float* d = &bt[il * 34 + jq * 8];
                d[0] = a.x;  d[1] = a.y;  d[2] = a.z;  d[3] = a.w;
                d[4] = b4.x; d[5] = b4.y; d[6] = b4.z; d[7] = b4.w;
            }
            {   // stage h tile [64 i][64 k] transposed, BN2+ReLU, pad stride 68
                int kc = tid >> 2, iq = tid & 3;
                float sc = sc2[kc], sh = sh2[kc];
                const float4* p = (const float4*)(c2 + ((size_t)n * C2 + kc) * LEN + ib + iq * 16);
#pragma unroll
                for (int r = 0; r < 4; ++r) {
                    float4 hv = p[r];
                    int i0 = iq * 16 + r * 4;
                    ht[(i0 + 0) * 68 + kc] = fmaxf(0.f, hv.x * sc + sh);
                    ht[(i0 + 1) * 68 + kc] = fmaxf(0.f, hv.y * sc + sh);
                    ht[(i0 + 2) * 68 + kc] = fmaxf(0.f, hv.z * sc + sh);
                    ht[(i0 + 3) * 68 + kc] = fmaxf(0.f, hv.w * sc + sh);
                }
            }
            __syncthreads();
#pragma unroll 4
            for (int i = 0; i < 64; ++i) {
                float2 bv = *(const float2*)&bt[i * 34 + jj];
                float4 hv = *(const float4*)&ht[i * 68 + kk];
                mx[0][0] = fmaxf(mx[0][0], bv.x * hv.x);
                mx[0][1] = fmaxf(mx[0][1], bv.x * hv.y);
                mx[0][2] = fmaxf(mx[0][2], bv.x * hv.z);
                mx[0][3] = fmaxf(mx[0][3], bv.x * hv.w);
                mx[1][0] = fmaxf(mx[1][0], bv.y * hv.x);
                mx[1][1] = fmaxf(mx[1][1], bv.y * hv.y);
                mx[1][2] = fmaxf(mx[1][2], bv.y * hv.z);
                mx[1][3] = fmaxf(mx[1][3], bv.y * hv.w);
            }
            __syncthreads();
        }
#pragma unroll
        for (int a = 0; a < 2; ++a)
#pragma unroll
            for (int c = 0; c < 4; ++c) {
                int j = jbase + jj + a, k = kk + c;
                atomicMax((unsigned int*)&z[((size_t)n * NODES + j) * 64 + k],
                          __float_as_uint(mx[a][c]));
            }
    }
    grid.sync();

    // ================= Phase D: FC1 halves -> zzp[kq][n][f] (no atomics)
    if (b < 200) {
        int f = b % 100, kq = b / 100;
        int base = kq * 4096;

        float acc[16];
#pragma unroll
        for (int nn = 0; nn < 16; ++nn) acc[nn] = 0.f;

        for (int q = 0; q < 16; ++q) {
            int idx = base + q * 256 + tid;
            float wv = w1[(size_t)f * 8192 + idx];
#pragma unroll
            for (int nn = 0; nn < 16; ++nn)
                acc[nn] += wv * z[(size_t)nn * 8192 + idx];
        }

        float* red = smem;   // 4*16
        for (int nn = 0; nn < 16; ++nn) {
            float s = acc[nn];
#pragma unroll
            for (int off = 32; off >= 1; off >>= 1) s += __shfl_xor(s, off);
            if (lane == 0) red[wave * 16 + nn] = s;
        }
        __syncthreads();
        if (tid < 16)
            zzp[(size_t)(kq * 16 + tid) * 100 + f]
                = red[tid] + red[16 + tid] + red[32 + tid] + red[48 + tid];
    }
    grid.sync();

    // ================= Phase E: +b1, BN3 over batch, ReLU, FC2 (+b2)
    if (b < 16) {
        int n = b;
        float* zzl = smem;          // 1600
        float* sc3 = smem + 1600;   // 100
        float* sh3 = smem + 1700;   // 100

        for (int idx = tid; idx < BATCH * NF1; idx += 256) {
            int f = idx % NF1;
            zzl[idx] = zzp[idx] + zzp[1600 + idx] + b1[f];
        }
        __syncthreads();
        if (tid < NF1) {
            float s = 0.f, q = 0.f;
#pragma unroll
            for (int m = 0; m < BATCH; ++m) {
                float v = zzl[m * NF1 + tid];
                s += v; q += v * v;
            }
            float mean = s * (1.f / 16.f);
            float var  = q * (1.f / 16.f) - mean * mean;
            float rs   = rsqrtf(var + EPS);
            float sc   = g3[tid] * rs;
            sc3[tid] = sc;
            sh3[tid] = b3[tid] - mean * sc;
        }
        __syncthreads();
        for (int idx = tid; idx < BATCH * NF1; idx += 256) {
            int f = idx % NF1;
            zzl[idx] = fmaxf(0.f, zzl[idx] * sc3[f] + sh3[f]);
        }
        __syncthreads();
        if (tid < NF2) {
            float acc = b2[tid];
            const float* wr = w2 + (size_t)tid * NF1;
            const float* zr = zzl + n * NF1;
#pragma unroll 4
            for (int f = 0; f < NF1; ++f)
                acc += zr[f] * wr[f];
            out[n * NF2 + tid] = acc;
        }
    }
}

extern "C" void kernel_launch(void* const* d_in, const int* in_sizes, int n_in,
                              void* d_out, int out_size, void* d_ws, size_t ws_size,
                              hipStream_t stream) {
    const float* x    = (const float*)d_in[0];
    const float* bmat = (const float*)d_in[1];
    const float* c1w  = (const float*)d_in[2];
    const float* c1b  = (const float*)d_in[3];
    const float* g1   = (const float*)d_in[4];
    const float* bb1  = (const float*)d_in[5];
    const float* c2w  = (const float*)d_in[6];
    const float* c2b  = (const float*)d_in[7];
    const float* g2   = (const float*)d_in[8];
    const float* bb2  = (const float*)d_in[9];
    const float* w1   = (const float*)d_in[10];
    const float* b1   = (const float*)d_in[11];
    const float* g3   = (const float*)d_in[12];
    const float* b3   = (const float*)d_in[13];
    const float* w2   = (const float*)d_in[14];
    const float* b2   = (const float*)d_in[15];
    float* out = (float*)d_out;
    float* ws  = (float*)d_ws;

    void* args[] = {
        (void*)&x,   (void*)&bmat, (void*)&c1w, (void*)&c1b,
        (void*)&g1,  (void*)&bb1,  (void*)&c2w, (void*)&c2b,
        (void*)&g2,  (void*)&bb2,  (void*)&w1,  (void*)&b1,
        (void*)&g3,  (void*)&b3,   (void*)&w2,  (void*)&b2,
        (void*)&out, (void*)&ws
    };
    hipLaunchCooperativeKernel((void*)fused, dim3(256), dim3(256), args, 0, stream);
}

// Round 2
// 208.376 us; speedup vs baseline: 1.3770x; 1.3770x over previous
//
#include <hip/hip_runtime.h>

#define EPS 1e-5f

#define BATCH 16
#define LEN   1024
#define C0    8
#define C1    32
#define C2    64
#define NODES 128
#define NF1   100
#define NF2   128

// workspace layout (float offsets). Every word read is written earlier in the
// same iteration (counters zeroed by kB before kC uses them) — no memset.
#define OFF_C1   0          // 16*32*1024 = 524288
#define OFF_C2   524288     // 16*64*1024 = 1048576
#define OFF_S1P  1572864    // 256 blocks * 64
#define OFF_S2P  1589248    // 256 blocks * 128
#define OFF_ZP   1622016    // 4 is * 16 n * 8192 = 524288
#define OFF_ZZP  2146304    // 4 jt * 16 n * 100 = 6400
#define OFF_CNT  2152704    // 65 uints

// ---------------- kA: conv1 (8->32, K=5, pad 2) + bias -> c1, BN1 block partials
__global__ __launch_bounds__(256)
void kA(const float* __restrict__ x, const float* __restrict__ w,
        const float* __restrict__ bias, float* __restrict__ c1,
        float* __restrict__ s1p) {
    int tid = threadIdx.x, b = blockIdx.x;
    int lane = tid & 63, wave = tid >> 6;
    int n = b >> 4, lt = b & 15;
    int l = lt * 64 + lane;
    int cg8 = __builtin_amdgcn_readfirstlane(wave * 8);

    float xr[5][8];
#pragma unroll
    for (int dl = 0; dl < 5; ++dl) {
        int lw = l + dl - 2;
        if (lw >= 0 && lw < LEN) {
            const float4* p = (const float4*)(x + ((size_t)n * LEN + lw) * C0);
            float4 a = p[0], b4 = p[1];
            xr[dl][0] = a.x;  xr[dl][1] = a.y;  xr[dl][2] = a.z;  xr[dl][3] = a.w;
            xr[dl][4] = b4.x; xr[dl][5] = b4.y; xr[dl][6] = b4.z; xr[dl][7] = b4.w;
        } else {
#pragma unroll
            for (int ci = 0; ci < 8; ++ci) xr[dl][ci] = 0.f;
        }
    }
#pragma unroll
    for (int u = 0; u < 8; ++u) {
        int c = cg8 + u;
        float acc = bias[c];
        const float* wc = w + c * 40;
#pragma unroll
        for (int ci = 0; ci < 8; ++ci)
#pragma unroll
            for (int dl = 0; dl < 5; ++dl)
                acc += xr[dl][ci] * wc[ci * 5 + dl];
        c1[((size_t)n * C1 + c) * LEN + l] = acc;

        float s = acc, q = acc * acc;
#pragma unroll
        for (int off = 32; off >= 1; off >>= 1) {
            s += __shfl_xor(s, off);
            q += __shfl_xor(q, off);
        }
        if (lane == 0) {
            s1p[b * 64 + c * 2]     = s;
            s1p[b * 64 + c * 2 + 1] = q;
        }
    }
}

// ---------------- kB: BN1 reduce; BN1+ReLU -> conv2 (32->64) -> c2, BN2 partials; zero counters
__global__ __launch_bounds__(256)
void kB(const float* __restrict__ c1, const float* __restrict__ w,
        const float* __restrict__ bias,
        const float* __restrict__ g1, const float* __restrict__ bb1,
        const float* __restrict__ s1p,
        float* __restrict__ c2, float* __restrict__ s2p,
        unsigned* __restrict__ cnt) {
    int tid = threadIdx.x, b = blockIdx.x;
    int lane = tid & 63, wave = tid >> 6;

    if (b == 0 && tid < 65) cnt[tid] = 0u;

    __shared__ float sc1[32], sh1[32];
    __shared__ __align__(16) float a1[32 * 68];
    __shared__ float redw[256];

    // reduce s1p: wave w sums blocks w*64..+63 for value 'lane' (coalesced, 8 accs)
    {
        float a0=0,a1_=0,a2=0,a3=0,a4=0,a5=0,a6=0,a7=0;
        int b0 = wave * 64;
        for (int i = 0; i < 64; i += 8) {
            a0  += s1p[(size_t)(b0+i  ) * 64 + lane];
            a1_ += s1p[(size_t)(b0+i+1) * 64 + lane];
            a2  += s1p[(size_t)(b0+i+2) * 64 + lane];
            a3  += s1p[(size_t)(b0+i+3) * 64 + lane];
            a4  += s1p[(size_t)(b0+i+4) * 64 + lane];
            a5  += s1p[(size_t)(b0+i+5) * 64 + lane];
            a6  += s1p[(size_t)(b0+i+6) * 64 + lane];
            a7  += s1p[(size_t)(b0+i+7) * 64 + lane];
        }
        redw[wave * 64 + lane] = ((a0+a1_)+(a2+a3)) + ((a4+a5)+(a6+a7));
    }
    __syncthreads();
    if (tid < 64)
        redw[tid] = redw[tid] + redw[64 + tid] + redw[128 + tid] + redw[192 + tid];
    __syncthreads();
    if (tid < 32) {
        float s = redw[tid * 2], q = redw[tid * 2 + 1];
        float mean = s * (1.f / 16384.f);
        float var  = q * (1.f / 16384.f) - mean * mean;
        float rs   = rsqrtf(var + EPS);
        float sc   = g1[tid] * rs;
        sc1[tid] = sc;
        sh1[tid] = bb1[tid] - mean * sc;
    }
    __syncthreads();

    int n = b >> 4, lt = b & 15;
    int lbase = lt * 64;

    for (int idx = tid; idx < 32 * 68; idx += 256) {
        int ci = idx / 68, lo = idx - ci * 68;
        int lg = lbase + lo - 2;
        float v = 0.f;
        if (lg >= 0 && lg < LEN) v = c1[((size_t)n * C1 + ci) * LEN + lg];
        a1[idx] = fmaxf(0.f, v * sc1[ci] + sh1[ci]);
    }
    __syncthreads();

    int l = lane;
    int cobase = __builtin_amdgcn_readfirstlane(wave * 16);

    float acc[16];
#pragma unroll
    for (int u = 0; u < 16; ++u) acc[u] = bias[cobase + u];

    for (int ci = 0; ci < 32; ++ci) {
        float v0 = a1[ci * 68 + l + 0];
        float v1 = a1[ci * 68 + l + 1];
        float v2 = a1[ci * 68 + l + 2];
        float v3 = a1[ci * 68 + l + 3];
        float v4 = a1[ci * 68 + l + 4];
#pragma unroll
        for (int u = 0; u < 16; ++u) {
            const float* wp = w + ((size_t)(cobase + u) * 32 + ci) * 5;
            acc[u] += v0 * wp[0] + v1 * wp[1] + v2 * wp[2] + v3 * wp[3] + v4 * wp[4];
        }
    }

    int lg = lbase + l;
#pragma unroll
    for (int u = 0; u < 16; ++u)
        c2[((size_t)n * C2 + cobase + u) * LEN + lg] = acc[u];

    for (int u = 0; u < 16; ++u) {
        float s = acc[u], q = acc[u] * acc[u];
#pragma unroll
        for (int off = 32; off >= 1; off >>= 1) {
            s += __shfl_xor(s, off);
            q += __shfl_xor(q, off);
        }
        if (lane == 0) {
            int c = cobase + u;
            s2p[b * 128 + c * 2]     = s;
            s2p[b * 128 + c * 2 + 1] = q;
        }
    }
}

// ---------------- kC: BN2 reduce; BN2+ReLU + pooling partial max -> zp;
// last block per (n,jt): z=max(zp[0..3]), FC1 slice -> zzp; last overall: BN3+FC2 -> out
__global__ __launch_bounds__(256)
void kC(const float* __restrict__ bmat, const float* __restrict__ c2,
        const float* __restrict__ g2, const float* __restrict__ bb2,
        const float* __restrict__ s2p,
        const float* __restrict__ w1, const float* __restrict__ b1f,
        const float* __restrict__ g3, const float* __restrict__ b3,
        const float* __restrict__ w2, const float* __restrict__ b2f,
        float* __restrict__ zp, float* __restrict__ zzp,
        unsigned* __restrict__ cnt, float* __restrict__ out) {
    int tid = threadIdx.x, b = blockIdx.x;
    int n = b >> 4, is = (b >> 2) & 3, jt = b & 3;

    __shared__ __align__(16) float smem[6656];
    __shared__ unsigned sflag;

    float* sc2  = smem;          // 64
    float* sh2  = smem + 64;     // 64
    float* bt   = smem + 128;    // 64*34 = 2176
    float* ht   = smem + 2304;   // 64*68 = 4352
    float* red2 = smem + 128;    // 256, used before bt staging

    // BN2 reduce: 128 values over 256 blocks, two halves, 8 accs
    {
        int v = tid & 127, half = tid >> 7;
        float a0=0,a1=0,a2=0,a3=0,a4=0,a5=0,a6=0,a7=0;
        int b0 = half * 128;
        for (int i = 0; i < 128; i += 8) {
            a0 += s2p[(size_t)(b0+i  ) * 128 + v];
            a1 += s2p[(size_t)(b0+i+1) * 128 + v];
            a2 += s2p[(size_t)(b0+i+2) * 128 + v];
            a3 += s2p[(size_t)(b0+i+3) * 128 + v];
            a4 += s2p[(size_t)(b0+i+4) * 128 + v];
            a5 += s2p[(size_t)(b0+i+5) * 128 + v];
            a6 += s2p[(size_t)(b0+i+6) * 128 + v];
            a7 += s2p[(size_t)(b0+i+7) * 128 + v];
        }
        red2[half * 128 + v] = ((a0+a1)+(a2+a3)) + ((a4+a5)+(a6+a7));
    }
    __syncthreads();
    if (tid < 128) red2[tid] += red2[128 + tid];
    __syncthreads();
    if (tid < 64) {
        float s = red2[tid * 2], q = red2[tid * 2 + 1];
        float mean = s * (1.f / 16384.f);
        float var  = q * (1.f / 16384.f) - mean * mean;
        float rs   = rsqrtf(var + EPS);
        float sc   = g2[tid] * rs;
        sc2[tid] = sc;
        sh2[tid] = bb2[tid] - mean * sc;
    }
    __syncthreads();

    int jbase = jt * 32;
    int ibase0 = is * 256;

    float mx[2][4];
#pragma unroll
    for (int a = 0; a < 2; ++a)
#pragma unroll
        for (int c = 0; c < 4; ++c) mx[a][c] = 0.f;

    int jj = (tid >> 4) * 2, kk = (tid & 15) * 4;

    for (int ic = 0; ic < 4; ++ic) {
        int ib = ibase0 + ic * 64;
        {   // stage b tile [64 i][32 j], pad stride 34
            int il = tid >> 2, jq = tid & 3;
            const float4* p = (const float4*)(bmat + ((size_t)n * LEN + ib + il) * NODES + jbase + jq * 8);
            float4 a = p[0], b4 = p[1];
            float* d = &bt[il * 34 + jq * 8];
            d[0] = a.x;  d[1] = a.y;  d[2] = a.z;  d[3] = a.w;
            d[4] = b4.x; d[5] = b4.y; d[6] = b4.z; d[7] = b4.w;
        }
        {   // stage h tile [64 i][64 k] transposed, BN2+ReLU, pad stride 68
            int kc = tid >> 2, iq = tid & 3;
            float sc = sc2[kc], sh = sh2[kc];
            const float4* p = (const float4*)(c2 + ((size_t)n * C2 + kc) * LEN + ib + iq * 16);
#pragma unroll
            for (int r = 0; r < 4; ++r) {
                float4 hv = p[r];
                int i0 = iq * 16 + r * 4;
                ht[(i0 + 0) * 68 + kc] = fmaxf(0.f, hv.x * sc + sh);
                ht[(i0 + 1) * 68 + kc] = fmaxf(0.f, hv.y * sc + sh);
                ht[(i0 + 2) * 68 + kc] = fmaxf(0.f, hv.z * sc + sh);
                ht[(i0 + 3) * 68 + kc] = fmaxf(0.f, hv.w * sc + sh);
            }
        }
        __syncthreads();
#pragma unroll 4
        for (int i = 0; i < 64; ++i) {
            float2 bv = *(const float2*)&bt[i * 34 + jj];
            float4 hv = *(const float4*)&ht[i * 68 + kk];
            mx[0][0] = fmaxf(mx[0][0], bv.x * hv.x);
            mx[0][1] = fmaxf(mx[0][1], bv.x * hv.y);
            mx[0][2] = fmaxf(mx[0][2], bv.x * hv.z);
            mx[0][3] = fmaxf(mx[0][3], bv.x * hv.w);
            mx[1][0] = fmaxf(mx[1][0], bv.y * hv.x);
            mx[1][1] = fmaxf(mx[1][1], bv.y * hv.y);
            mx[1][2] = fmaxf(mx[1][2], bv.y * hv.z);
            mx[1][3] = fmaxf(mx[1][3], bv.y * hv.w);
        }
        __syncthreads();
    }

    // partial max -> zp[is][n][j*64+k]  (plain stores, deterministic)
    {
        float* zpb = zp + ((size_t)(is * 16 + n)) * 8192;
        *(float4*)&zpb[(jbase + jj + 0) * 64 + kk] = make_float4(mx[0][0], mx[0][1], mx[0][2], mx[0][3]);
        *(float4*)&zpb[(jbase + jj + 1) * 64 + kk] = make_float4(mx[1][0], mx[1][1], mx[1][2], mx[1][3]);
    }

    // -------- last-block-per-(n,jt) finisher (no spinning: atomic ticket)
    __syncthreads();
    __threadfence();                       // release zp (agent scope: L2 wb)
    __syncthreads();
    if (tid == 0) {
        unsigned prev = atomicAdd(&cnt[n * 4 + jt], 1u);
        sflag = (prev == 3u) ? 1u : 0u;
    }
    __syncthreads();
    if (!sflag) return;
    __threadfence();                       // acquire zp written by other blocks

    // z chunk (2048: j in [jbase,jbase+32), all k) = max over is; stage in LDS
    float* zl = smem;                      // 2048 floats (pool smem done)
    {
        size_t base = (size_t)n * 8192 + jbase * 64;
#pragma unroll
        for (int e = 0; e < 8; ++e) {
            int idx = e * 256 + tid;
            float v0 = zp[base + idx];
            float v1 = zp[base + idx + 16 * 8192];
            float v2 = zp[base + idx + 32 * 8192];
            float v3 = zp[base + idx + 48 * 8192];
            zl[idx] = fmaxf(fmaxf(v0, v1), fmaxf(v2, v3));
        }
    }
    __syncthreads();

    // FC1 slice: zzp[jt][n][f] = sum over this 2048-chunk of z * w1[f][chunk]
    {
        int wv = tid >> 6, ln = tid & 63;
        float4 zr[8];
#pragma unroll
        for (int e = 0; e < 8; ++e)
            zr[e] = *(float4*)&zl[e * 256 + ln * 4];

        for (int t = 0; t < 25; ++t) {
            int f = wv * 25 + t;
            const float* wp = w1 + (size_t)f * 8192 + jbase * 64;
            float s = 0.f;
#pragma unroll
            for (int e = 0; e < 8; ++e) {
                float4 w4 = *(const float4*)&wp[e * 256 + ln * 4];
                s += zr[e].x * w4.x + zr[e].y * w4.y + zr[e].z * w4.z + zr[e].w * w4.w;
            }
#pragma unroll
            for (int off = 32; off >= 1; off >>= 1) s += __shfl_xor(s, off);
            if (ln == 0) zzp[((size_t)jt * 16 + n) * 100 + f] = s;
        }
    }

    // -------- globally-last finisher: BN3 + FC2
    __syncthreads();
    __threadfence();                       // release zzp
    __syncthreads();
    if (tid == 0) {
        unsigned p2 = atomicAdd(&cnt[64], 1u);
        sflag = (p2 == 63u) ? 1u : 0u;
    }
    __syncthreads();
    if (!sflag) return;
    __threadfence();                       // acquire zzp

    float* zzl = smem;                     // 1600
    float* sc3 = smem + 1600;              // 100
    float* sh3 = smem + 1700;              // 100

    for (int idx = tid; idx < BATCH * NF1; idx += 256) {
        int f = idx % NF1;
        zzl[idx] = zzp[idx] + zzp[1600 + idx] + zzp[3200 + idx] + zzp[4800 + idx] + b1f[f];
    }
    __syncthreads();
    if (tid < NF1) {
        float s = 0.f, q = 0.f;
#pragma unroll
        for (int m = 0; m < BATCH; ++m) {
            float v = zzl[m * NF1 + tid];
            s += v; q += v * v;
        }
        float mean = s * (1.f / 16.f);
        float var  = q * (1.f / 16.f) - mean * mean;
        float rs   = rsqrtf(var + EPS);
        float sc   = g3[tid] * rs;
        sc3[tid] = sc;
        sh3[tid] = b3[tid] - mean * sc;
    }
    __syncthreads();
    for (int idx = tid; idx < BATCH * NF1; idx += 256) {
        int f = idx % NF1;
        zzl[idx] = fmaxf(0.f, zzl[idx] * sc3[f] + sh3[f]);
    }
    __syncthreads();

    // FC2: o = tid&127, half of batch per thread
    {
        int o = tid & 127, half = tid >> 7;
        float acc[8];
#pragma unroll
        for (int nn = 0; nn < 8; ++nn) acc[nn] = b2f[o];
        const float* wr = w2 + (size_t)o * NF1;
        for (int f = 0; f < NF1; ++f) {
            float wvv = wr[f];
#pragma unroll
            for (int nn = 0; nn < 8; ++nn)
                acc[nn] += zzl[(half * 8 + nn) * NF1 + f] * wvv;
        }
#pragma unroll
        for (int nn = 0; nn < 8; ++nn)
            out[(half * 8 + nn) * NF2 + o] = acc[nn];
    }
}

extern "C" void kernel_launch(void* const* d_in, const int* in_sizes, int n_in,
                              void* d_out, int out_size, void* d_ws, size_t ws_size,
                              hipStream_t stream) {
    const float* x    = (const float*)d_in[0];
    const float* bmat = (const float*)d_in[1];
    const float* c1w  = (const float*)d_in[2];
    const float* c1b  = (const float*)d_in[3];
    const float* g1   = (const float*)d_in[4];
    const float* bb1  = (const float*)d_in[5];
    const float* c2w  = (const float*)d_in[6];
    const float* c2b  = (const float*)d_in[7];
    const float* g2   = (const float*)d_in[8];
    const float* bb2  = (const float*)d_in[9];
    const float* w1   = (const float*)d_in[10];
    const float* b1   = (const float*)d_in[11];
    const float* g3   = (const float*)d_in[12];
    const float* b3   = (const float*)d_in[13];
    const float* w2   = (const float*)d_in[14];
    const float* b2   = (const float*)d_in[15];
    float* out = (float*)d_out;
    float* ws  = (float*)d_ws;

    float*    c1  = ws + OFF_C1;
    float*    c2  = ws + OFF_C2;
    float*    s1p = ws + OFF_S1P;
    float*    s2p = ws + OFF_S2P;
    float*    zp  = ws + OFF_ZP;
    float*    zzp = ws + OFF_ZZP;
    unsigned* cnt = (unsigned*)(ws + OFF_CNT);

    kA<<<256, 256, 0, stream>>>(x, c1w, c1b, c1, s1p);
    kB<<<256, 256, 0, stream>>>(c1, c2w, c2b, g1, bb1, s1p, c2, s2p, cnt);
    kC<<<256, 256, 0, stream>>>(bmat, c2, g2, bb2, s2p, w1, b1, g3, b3, w2, b2,
                                zp, zzp, cnt, out);
}